// Round 3
// baseline (3376.955 us; speedup 1.0000x reference)
//
#include <hip/hip_runtime.h>

#define LDSW 40
#define SCAN_P 128
#define SCAN_L 64

typedef short short8 __attribute__((ext_vector_type(8)));
typedef float floatx4 __attribute__((ext_vector_type(4)));
typedef unsigned short u16;

__device__ __forceinline__ u16 bf16_rne(float v) {
    unsigned int u = __float_as_uint(v);
    u = u + 0x7fffu + ((u >> 16) & 1u);
    return (u16)(u >> 16);
}
__device__ __forceinline__ float bf16_to_f(u16 h) {
    return __uint_as_float(((unsigned int)h) << 16);
}
__device__ __forceinline__ float sigm(float x) { return 1.f / (1.f + expf(-x)); }
__device__ __forceinline__ float logsig(float x) {
    const float l = log1pf(expf(-fabsf(x)));
    return x >= 0.f ? -l : x - l;
}

// fp32 -> bf16 hi/lo split of 8 contiguous elements
__device__ __forceinline__ void cvt8(const float* p, short8& h8, short8& l8) {
    const float4 a = *(const float4*)p;
    const float4 b = *(const float4*)(p + 4);
    const float v[8] = {a.x, a.y, a.z, a.w, b.x, b.y, b.z, b.w};
#pragma unroll
    for (int j = 0; j < 8; ++j) {
        const u16 hh = bf16_rne(v[j]);
        h8[j] = (short)hh;
        l8[j] = (short)bf16_rne(v[j] - bf16_to_f(hh));
    }
}
__device__ __forceinline__ void cvt8h(const float* p, short8& h8) {
    const float4 a = *(const float4*)p;
    const float4 b = *(const float4*)(p + 4);
    const float v[8] = {a.x, a.y, a.z, a.w, b.x, b.y, b.z, b.w};
#pragma unroll
    for (int j = 0; j < 8; ++j) h8[j] = (short)bf16_rne(v[j]);
}

// ---------------------------------------------------------------------------
// C[M,N] = A[M,K] @ B[N,K]^T + bias.  Operands fp32 in HBM, split to bf16
// hi/lo during LDS staging.  NPROD=3: AhBh+AhBl+AlBh (~2^-17 rel).  NPROD=1:
// AhBh.  AFMT=1: A is pre-split bf16-hi (u16).  EPI: 0 plain, 1 v*=Q[idx],
// 2 gelu(tanh).  ACC: C += v.  ST: 0 fp32 store, 1 bf16 hi/lo split store.
// 128x128 tile, 4 waves 2x2, 64x64/wave, 16x16x32 MFMA (C/D m89-verified).
// ---------------------------------------------------------------------------
template <int AFMT, int NPROD, int EPI, int ACC, int ST>
__global__ __launch_bounds__(256, 2) void gemm_f32(
    const float* __restrict__ Af, const u16* __restrict__ Au,
    const float* __restrict__ Bf, const float* __restrict__ bias,
    float* C, u16* Chi, u16* Clo, const float* Q,
    long ldA, long ldB, long ldC, int K)
{
    __shared__ __align__(16) u16 sAh[128 * LDSW];
    __shared__ __align__(16) u16 sBh[128 * LDSW];
    __shared__ __align__(16) u16 sAl[NPROD == 3 ? 128 * LDSW : 8];
    __shared__ __align__(16) u16 sBl[NPROD == 3 ? 128 * LDSW : 8];

    const int tid  = threadIdx.x;
    const int lane = tid & 63;
    const int wid  = tid >> 6;
    const int wm   = (wid >> 1) << 6;
    const int wn   = (wid & 1) << 6;
    const int m16  = lane & 15;
    const int kq   = lane >> 4;
    const int koff = kq << 3;
    const long bM  = (long)blockIdx.y << 7;
    const long bN  = (long)blockIdx.x << 7;
    const int sr   = tid >> 2;
    const int sc   = (tid & 3) << 3;

    floatx4 acc[4][4] = {};

#pragma unroll 1
    for (int k0 = 0; k0 < K; k0 += 32) {
        __syncthreads();
#pragma unroll
        for (int i = 0; i < 2; ++i) {
            const int r  = sr + (i << 6);
            const int ls = r * LDSW + sc;
            if constexpr (AFMT == 0) {
                if constexpr (NPROD == 3) {
                    short8 h8, l8;
                    cvt8(Af + (bM + r) * ldA + k0 + sc, h8, l8);
                    *(short8*)&sAh[ls] = h8;
                    *(short8*)&sAl[ls] = l8;
                } else {
                    short8 h8;
                    cvt8h(Af + (bM + r) * ldA + k0 + sc, h8);
                    *(short8*)&sAh[ls] = h8;
                }
            } else {
                *(short8*)&sAh[ls] = *(const short8*)(Au + (bM + r) * ldA + k0 + sc);
            }
            if constexpr (NPROD == 3) {
                short8 h8, l8;
                cvt8(Bf + (bN + r) * ldB + k0 + sc, h8, l8);
                *(short8*)&sBh[ls] = h8;
                *(short8*)&sBl[ls] = l8;
            } else {
                short8 h8;
                cvt8h(Bf + (bN + r) * ldB + k0 + sc, h8);
                *(short8*)&sBh[ls] = h8;
            }
        }
        __syncthreads();

        short8 ah[4], bh[4];
#pragma unroll
        for (int t = 0; t < 4; ++t) {
            ah[t] = *(const short8*)&sAh[(wm + t * 16 + m16) * LDSW + koff];
            bh[t] = *(const short8*)&sBh[(wn + t * 16 + m16) * LDSW + koff];
        }
#pragma unroll
        for (int mi = 0; mi < 4; ++mi)
#pragma unroll
            for (int ni = 0; ni < 4; ++ni)
                acc[mi][ni] = __builtin_amdgcn_mfma_f32_16x16x32_bf16(ah[mi], bh[ni], acc[mi][ni], 0, 0, 0);

        if constexpr (NPROD == 3) {
            short8 al[4], bl[4];
#pragma unroll
            for (int t = 0; t < 4; ++t) {
                al[t] = *(const short8*)&sAl[(wm + t * 16 + m16) * LDSW + koff];
                bl[t] = *(const short8*)&sBl[(wn + t * 16 + m16) * LDSW + koff];
            }
#pragma unroll
            for (int mi = 0; mi < 4; ++mi)
#pragma unroll
                for (int ni = 0; ni < 4; ++ni)
                    acc[mi][ni] = __builtin_amdgcn_mfma_f32_16x16x32_bf16(ah[mi], bl[ni], acc[mi][ni], 0, 0, 0);
#pragma unroll
            for (int mi = 0; mi < 4; ++mi)
#pragma unroll
                for (int ni = 0; ni < 4; ++ni)
                    acc[mi][ni] = __builtin_amdgcn_mfma_f32_16x16x32_bf16(al[mi], bh[ni], acc[mi][ni], 0, 0, 0);
        }
    }

    float bv[4];
#pragma unroll
    for (int ni = 0; ni < 4; ++ni) bv[ni] = bias ? bias[bN + wn + ni * 16 + m16] : 0.f;

#pragma unroll
    for (int mi = 0; mi < 4; ++mi) {
#pragma unroll
        for (int ni = 0; ni < 4; ++ni) {
#pragma unroll
            for (int r = 0; r < 4; ++r) {
                // C/D: col = lane&15, row = (lane>>4)*4 + reg  [m89-verified]
                const long grow = bM + wm + mi * 16 + (kq << 2) + r;
                const long gcol = bN + wn + ni * 16 + m16;
                const long idx  = grow * ldC + gcol;
                float v = acc[mi][ni][r] + bv[ni];
                if constexpr (ACC) v += C[idx];
                if constexpr (EPI == 1) v *= Q[idx];
                if constexpr (EPI == 2)
                    v = 0.5f * v * (1.f + tanhf(0.7978845608028654f * (v + 0.044715f * v * v * v)));
                if constexpr (ST == 1) {
                    const u16 h = bf16_rne(v);
                    Chi[idx] = h;
                    Clo[idx] = bf16_rne(v - bf16_to_f(h));
                } else {
                    C[idx] = v;
                }
            }
        }
    }
}

// ---------------------------------------------------------------------------
// za(slabA), zg(d_out) -> a(slabA), q=sqrt(1-exp(2 log_a))*g (d_out), in place
__global__ __launch_bounds__(256) void aq_kernel(
    float* za, float* zg, const float* __restrict__ lam)
{
    const long i = ((long)blockIdx.x * 256 + threadIdx.x) * 4;
    const int  c = (int)(i & 2047);
    const float4 zav = *(const float4*)(za + i);
    const float4 zgv = *(const float4*)(zg + i);
    const float4 lmv = *(const float4*)(lam + c);
    float4 av, qv;
    const float zaa[4] = {zav.x, zav.y, zav.z, zav.w};
    const float zga[4] = {zgv.x, zgv.y, zgv.z, zgv.w};
    const float lma[4] = {lmv.x, lmv.y, lmv.z, lmv.w};
    float aa[4], qa[4];
#pragma unroll
    for (int j = 0; j < 4; ++j) {
        const float r  = sigm(zaa[j]);
        const float g  = sigm(zga[j]);
        const float la = 8.f * r * logsig(lma[j]);
        aa[j] = expf(la);
        qa[j] = sqrtf(fmaxf(1.f - expf(2.f * la), 0.f)) * g;
    }
    av.x = aa[0]; av.y = aa[1]; av.z = aa[2]; av.w = aa[3];
    qv.x = qa[0]; qv.y = qa[1]; qv.z = qa[2]; qv.w = qa[3];
    *(float4*)(za + i) = av;
    *(float4*)(zg + i) = qv;
}

// ---------------------------------------------------------------------------
// chunked scan over S (stride 2048): h_t = a_t h_{t-1} + b_t
__global__ __launch_bounds__(256) void scan_partial(
    const float* __restrict__ A, const float* __restrict__ B,
    float* __restrict__ Aagg, float* __restrict__ Bagg)
{
    const int c = blockIdx.x * 256 + threadIdx.x;
    const int p = blockIdx.y;
    const long base = (long)p * SCAN_L * 2048 + c;
    float Ar = 1.f, Br = 0.f;
    for (int t = 0; t < SCAN_L; ++t) {
        const float at = A[base + (long)t * 2048];
        const float bt = B[base + (long)t * 2048];
        Ar *= at;
        Br = Br * at + bt;
    }
    Aagg[p * 2048 + c] = Ar;
    Bagg[p * 2048 + c] = Br;
}

__global__ __launch_bounds__(256) void scan_combine(
    const float* __restrict__ Aagg, const float* __restrict__ Bagg,
    float* __restrict__ Hini)
{
    const int c = blockIdx.x * 256 + threadIdx.x;
    float h = 0.f;
    for (int p = 0; p < SCAN_P; ++p) {
        Hini[p * 2048 + c] = h;
        h = Aagg[p * 2048 + c] * h + Bagg[p * 2048 + c];
    }
}

// reads a (A) and b (B), writes h fp32 over A (element read before write)
__global__ __launch_bounds__(256) void scan_final(
    float* A, const float* __restrict__ B, const float* __restrict__ Hini)
{
    const int c = blockIdx.x * 256 + threadIdx.x;
    const int p = blockIdx.y;
    const long base = (long)p * SCAN_L * 2048 + c;
    float h = Hini[p * 2048 + c];
    for (int t = 0; t < SCAN_L; ++t) {
        const long idx = base + (long)t * 2048;
        h = A[idx] * h + B[idx];
        A[idx] = h;
    }
}

// ---------------------------------------------------------------------------
// v[j] = sum_d W[d,j] * w[d]   (chunked partials, then reduce)
__global__ __launch_bounds__(256) void vpart_kernel(
    const float* __restrict__ W, const float* __restrict__ w,
    float* __restrict__ part, long ldW, int dchunk)
{
    const int j  = blockIdx.x * 256 + threadIdx.x;
    const int d0 = blockIdx.y * dchunk;
    float s = 0.f;
    for (int d = 0; d < dchunk; ++d) s += W[(long)(d0 + d) * ldW + j] * w[d0 + d];
    part[(long)blockIdx.y * ldW + j] = s;
}

__global__ __launch_bounds__(256) void vreduce_kernel(
    const float* __restrict__ part, float* __restrict__ v, long ldW, int nch)
{
    const int j = blockIdx.x * 256 + threadIdx.x;
    float s = 0.f;
    for (int c = 0; c < nch; ++c) s += part[(long)c * ldW + j];
    v[j] = s;
}

__global__ __launch_bounds__(256) void dotc_kernel(
    const float* __restrict__ a, const float* __restrict__ b,
    const float* __restrict__ bias1, float* __restrict__ out)
{
    __shared__ float red[4];
    const int tid = threadIdx.x, lane = tid & 63, wid = tid >> 6;
    float s = 0.f;
    for (int d = tid; d < 2048; d += 256) s += a[d] * b[d];
#pragma unroll
    for (int off = 32; off > 0; off >>= 1) s += __shfl_down(s, off);
    if (lane == 0) red[wid] = s;
    __syncthreads();
    if (tid == 0) out[0] = red[0] + red[1] + red[2] + red[3] + bias1[0];
}

// ---------------------------------------------------------------------------
// zb[s] (+)= sum_{f<L} (uHi+uLo)[s,f] * v2s[f]  (+ zc on INIT)
template <int INIT>
__global__ __launch_bounds__(256) void zacc_kernel(
    const u16* __restrict__ uHi, const u16* __restrict__ uLo,
    const float* __restrict__ v2s, const float* __restrict__ zc,
    float* __restrict__ zb, int L)
{
    __shared__ float red[4];
    const int tid = threadIdx.x, lane = tid & 63, wid = tid >> 6;
    const long s = blockIdx.x;
    const long base = s * (long)L;
    float dot = 0.f;
    for (int f = tid; f < L; f += 256)
        dot += (bf16_to_f(uHi[base + f]) + bf16_to_f(uLo[base + f])) * v2s[f];
#pragma unroll
    for (int off = 32; off > 0; off >>= 1) dot += __shfl_down(dot, off);
    if (lane == 0) red[wid] = dot;
    __syncthreads();
    if (tid == 0) {
        const float t = red[0] + red[1] + red[2] + red[3];
        zb[s] = INIT ? (zc[0] + t) : (zb[s] + t);
    }
}

// ---------------------------------------------------------------------------
// gate1: z = h.v1 + zc1 ; g = u1<sigmoid(z) ; y = x + g*res1 ;
// rmsnorm -> x1 fp32 written over res1 (same buffer, per-row in place)
__global__ __launch_bounds__(256) void gate1_kernel(
    const float* __restrict__ x, float* res1x1,
    const float* __restrict__ h,
    const float* __restrict__ v1, const float* __restrict__ zc1,
    const float* __restrict__ u1,
    const float* __restrict__ nw, const float* __restrict__ nb)
{
    __shared__ float red[4];
    const int tid = threadIdx.x, lane = tid & 63, wid = tid >> 6;
    const long s = blockIdx.x;
    const long base = s * 2048;

    float dot = 0.f;
#pragma unroll
    for (int k = 0; k < 8; ++k) {
        const int d = tid + (k << 8);
        dot += h[base + d] * v1[d];
    }
#pragma unroll
    for (int off = 32; off > 0; off >>= 1) dot += __shfl_down(dot, off);
    if (lane == 0) red[wid] = dot;
    __syncthreads();
    const float z = red[0] + red[1] + red[2] + red[3] + zc1[0];
    __syncthreads();

    const float g = (u1[s] < sigm(z)) ? 1.f : 0.f;

    float yv[8];
    float ss = 0.f;
#pragma unroll
    for (int k = 0; k < 8; ++k) {
        const int d = tid + (k << 8);
        const float y = x[base + d] + g * res1x1[base + d];
        yv[k] = y;
        ss += y * y;
    }
#pragma unroll
    for (int off = 32; off > 0; off >>= 1) ss += __shfl_down(ss, off);
    if (lane == 0) red[wid] = ss;
    __syncthreads();
    const float inv = rsqrtf((red[0] + red[1] + red[2] + red[3]) * (1.f / 2048.f) + 1e-6f);

#pragma unroll
    for (int k = 0; k < 8; ++k) {
        const int d = tid + (k << 8);
        res1x1[base + d] = yv[k] * inv * nw[d] + nb[d];
    }
}

// gate2: g = u2<sigmoid(zb2[s]) ; y = x1 + g*res2 ; rmsnorm -> out (= x1 buf)
__global__ __launch_bounds__(256) void gate2_kernel(
    float* x1out, const float* __restrict__ res2,
    const float* __restrict__ zb2, const float* __restrict__ u2,
    const float* __restrict__ nw, const float* __restrict__ nb)
{
    __shared__ float red[4];
    const int tid = threadIdx.x, lane = tid & 63, wid = tid >> 6;
    const long s = blockIdx.x;
    const long base = s * 2048;

    const float g = (u2[s] < sigm(zb2[s])) ? 1.f : 0.f;

    float yv[8];
    float ss = 0.f;
#pragma unroll
    for (int k = 0; k < 8; ++k) {
        const int d = tid + (k << 8);
        const float y = x1out[base + d] + g * res2[base + d];
        yv[k] = y;
        ss += y * y;
    }
#pragma unroll
    for (int off = 32; off > 0; off >>= 1) ss += __shfl_down(ss, off);
    if (lane == 0) red[wid] = ss;
    __syncthreads();
    const float inv = rsqrtf((red[0] + red[1] + red[2] + red[3]) * (1.f / 2048.f) + 1e-6f);

#pragma unroll
    for (int k = 0; k < 8; ++k) {
        const int d = tid + (k << 8);
        x1out[base + d] = yv[k] * inv * nw[d] + nb[d];
    }
}

// ---------------------------------------------------------------------------
extern "C" void kernel_launch(void* const* d_in, const int* in_sizes, int n_in,
                              void* d_out, int out_size, void* d_ws, size_t ws_size,
                              hipStream_t stream)
{
    const float* x     = (const float*)d_in[0];
    const float* W_in  = (const float*)d_in[1];
    const float* b_in  = (const float*)d_in[2];
    const float* W_a   = (const float*)d_in[3];
    const float* b_a   = (const float*)d_in[4];
    const float* W_g   = (const float*)d_in[5];
    const float* b_g   = (const float*)d_in[6];
    const float* lam   = (const float*)d_in[7];
    const float* W_out = (const float*)d_in[8];
    const float* b_out = (const float*)d_in[9];
    const float* w1    = (const float*)d_in[10];
    const float* fb1   = (const float*)d_in[11];
    const float* w2    = (const float*)d_in[12];
    const float* fb2   = (const float*)d_in[13];
    const float* a1w   = (const float*)d_in[14];
    const float* a1b   = (const float*)d_in[15];
    const float* a2w   = (const float*)d_in[16];
    const float* a2b   = (const float*)d_in[17];
    const float* n1w   = (const float*)d_in[18];
    const float* n1b   = (const float*)d_in[19];
    const float* n2w   = (const float*)d_in[20];
    const float* n2b   = (const float*)d_in[21];
    const float* u1    = (const float*)d_in[22];
    const float* u2    = (const float*)d_in[23];
    (void)in_sizes; (void)n_in; (void)out_size;

    float* dob = (float*)d_out;          // 64 MiB fp32 scratch until final write

    char* ws = (char*)d_ws;
    size_t o = 0;
    auto take = [&](size_t bytes) -> char* {
        char* p = ws + o;
        o += (bytes + 255) & ~(size_t)255;
        return p;
    };

    float* Aagg = (float*)take((size_t)SCAN_P * 2048 * 4);
    float* Bagg = (float*)take((size_t)SCAN_P * 2048 * 4);
    float* Hini = (float*)take((size_t)SCAN_P * 2048 * 4);
    float* v1   = (float*)take(2048 * 4);
    float* v2   = (float*)take(8192 * 4);
    float* vp   = (float*)take(16 * 8192 * 4);
    float* zc1  = (float*)take(256);
    float* zc2  = (float*)take(256);
    float* zb2  = (float*)take(8192 * 4);

    float* slabA = (float*)take(64ull << 20);       // za -> a -> h -> u splits
    const bool pathA = ws_size >= o + (64ull << 20);
    float* slabB = nullptr;                          // res2 full  (path A)
    float* res2b = nullptr;                          // res2 block (path B)
    if (pathA) slabB = (float*)take(64ull << 20);
    else       res2b = (float*)take(16ull << 20);
    if (o > ws_size) return;  // diagnostic: absmax == max|ref| signature

    u16* uHi = (u16*)slabA;
    u16* uLo = uHi + (1u << 24);   // 16 Mi elements in both layouts

    const dim3 blk(256);

    // gate-logit vectors (exact fp32 path; gates never see GEMM error)
    vpart_kernel<<<dim3(8, 16), blk, 0, stream>>>(W_out, a1w, vp, 2048, 128);
    vreduce_kernel<<<8, blk, 0, stream>>>(vp, v1, 2048, 16);
    vpart_kernel<<<dim3(32, 16), blk, 0, stream>>>(w2, a2w, vp, 8192, 128);
    vreduce_kernel<<<32, blk, 0, stream>>>(vp, v2, 8192, 16);
    dotc_kernel<<<1, blk, 0, stream>>>(b_out, a1w, a1b, zc1);
    dotc_kernel<<<1, blk, 0, stream>>>(fb2, a2w, a2b, zc2);

    // za = x@W_a^T + b_a -> slabA ; zg = x@W_g^T + b_g -> d_out
    gemm_f32<0, 3, 0, 0, 0><<<dim3(16, 64), blk, 0, stream>>>(
        x, nullptr, W_a, b_a, slabA, nullptr, nullptr, nullptr, 2048, 2048, 2048, 2048);
    gemm_f32<0, 3, 0, 0, 0><<<dim3(16, 64), blk, 0, stream>>>(
        x, nullptr, W_g, b_g, dob, nullptr, nullptr, nullptr, 2048, 2048, 2048, 2048);

    // a (slabA), q (d_out)
    aq_kernel<<<16384, blk, 0, stream>>>(slabA, dob, lam);

    // b = q * (x@W_in^T + b_in) -> d_out (EPI=1 multiplies by Q in place)
    gemm_f32<0, 3, 1, 0, 0><<<dim3(16, 64), blk, 0, stream>>>(
        x, nullptr, W_in, b_in, dob, nullptr, nullptr, dob, 2048, 2048, 2048, 2048);

    // scan: a(slabA), b(d_out) -> h fp32 over slabA
    scan_partial<<<dim3(8, SCAN_P), blk, 0, stream>>>(slabA, dob, Aagg, Bagg);
    scan_combine<<<8, blk, 0, stream>>>(Aagg, Bagg, Hini);
    scan_final<<<dim3(8, SCAN_P), blk, 0, stream>>>(slabA, dob, Hini);

    // res1 = h@W_out^T + b_out -> d_out (b dead)
    gemm_f32<0, 1, 0, 0, 0><<<dim3(16, 64), blk, 0, stream>>>(
        slabA, nullptr, W_out, b_out, dob, nullptr, nullptr, nullptr, 2048, 2048, 2048, 2048);

    // gate1 + rmsnorm -> x1 fp32 in d_out (in place over res1)
    gate1_kernel<<<8192, blk, 0, stream>>>(x, dob, slabA, v1, zc1, u1, n1w, n1b);

    if (pathA) {
        // FFN over 4 F-chunks of 2048; u chunk as bf16 hi/lo in slabA
        for (int c = 0; c < 4; ++c) {
            const long f0 = (long)c * 2048;
            gemm_f32<0, 3, 2, 0, 1><<<dim3(16, 64), blk, 0, stream>>>(
                dob, nullptr, w1 + f0 * 2048, fb1 + f0,
                nullptr, uHi, uLo, nullptr, 2048, 2048, 2048, 2048);
            if (c == 0)
                zacc_kernel<1><<<8192, blk, 0, stream>>>(uHi, uLo, v2 + f0, zc2, zb2, 2048);
            else
                zacc_kernel<0><<<8192, blk, 0, stream>>>(uHi, uLo, v2 + f0, zc2, zb2, 2048);
            if (c == 0)
                gemm_f32<1, 1, 0, 0, 0><<<dim3(16, 64), blk, 0, stream>>>(
                    nullptr, uHi, w2 + f0, fb2, slabB, nullptr, nullptr, nullptr,
                    2048, 8192, 2048, 2048);
            else
                gemm_f32<1, 1, 0, 1, 0><<<dim3(16, 64), blk, 0, stream>>>(
                    nullptr, uHi, w2 + f0, nullptr, slabB, nullptr, nullptr, nullptr,
                    2048, 8192, 2048, 2048);
        }
        gate2_kernel<<<8192, blk, 0, stream>>>(dob, slabB, zb2, u2, n2w, n2b);
    } else {
        // FFN over 4 S-blocks of 2048; u block [2048 x 8192] as hi/lo in slabA
        for (int rb = 0; rb < 4; ++rb) {
            const long roff = (long)rb * 2048;
            gemm_f32<0, 3, 2, 0, 1><<<dim3(64, 16), blk, 0, stream>>>(
                dob + roff * 2048, nullptr, w1, fb1,
                nullptr, uHi, uLo, nullptr, 2048, 2048, 8192, 2048);
            zacc_kernel<1><<<2048, blk, 0, stream>>>(uHi, uLo, v2, zc2, zb2 + roff, 8192);
            gemm_f32<1, 1, 0, 0, 0><<<dim3(16, 16), blk, 0, stream>>>(
                nullptr, uHi, w2, fb2, res2b, nullptr, nullptr, nullptr,
                8192, 8192, 2048, 8192);
            gate2_kernel<<<2048, blk, 0, stream>>>(
                dob + roff * 2048, res2b, zb2 + roff, u2 + roff, n2w, n2b);
        }
    }
}